// Round 2
// baseline (394.484 us; speedup 1.0000x reference)
//
#include <hip/hip_runtime.h>

#define LAMBDA_COOR 5.0f
#define LAMBDA_NOOBJ 0.5f

// Round-0 layout (4 contiguous cell-groups per thread: conf mask lands in
// registers, zero gathers) restructured for deep memory-level parallelism:
// each half-thread-chunk issues 20 global_load_dwordx4 back-to-back (10 per
// array, 320B payload) before any consumer. __launch_bounds__(256,4) raises
// the VGPR cap to 128 so the whole batch stays live -> ~100KB in flight/CU
// vs ~3KB in the previous (28-32 VGPR) versions.
__global__ __launch_bounds__(256, 4) void yolo_loss_kernel(
    const float* __restrict__ outp, const float* __restrict__ tgt,
    float* __restrict__ loss, int n_groups, float inv_b)
{
    const int tid = blockIdx.x * blockDim.x + threadIdx.x;
    const int nth = gridDim.x * blockDim.x;
    float acc = 0.0f;

    for (int g0 = tid * 4; g0 < n_groups; g0 += nth * 4) {
        if (g0 + 4 <= n_groups) {
            // Two iterations of 2 groups (8 cells = 40 floats per array each).
            #pragma unroll 1   // keep the 20-load batches separate (VGPR cap)
            for (int it = 0; it < 2; ++it) {
                const float4* o4 = (const float4*)(outp + (size_t)(g0 + 2 * it) * 20);
                const float4* t4 = (const float4*)(tgt  + (size_t)(g0 + 2 * it) * 20);
                float4 ov[10], tv[10];
                #pragma unroll
                for (int i = 0; i < 10; ++i) ov[i] = o4[i];
                #pragma unroll
                for (int i = 0; i < 10; ++i) tv[i] = t4[i];

                float of[40], tf[40];
                #pragma unroll
                for (int i = 0; i < 10; ++i) {
                    of[4*i+0] = ov[i].x; of[4*i+1] = ov[i].y;
                    of[4*i+2] = ov[i].z; of[4*i+3] = ov[i].w;
                    tf[4*i+0] = tv[i].x; tf[4*i+1] = tv[i].y;
                    tf[4*i+2] = tv[i].z; tf[4*i+3] = tv[i].w;
                }

                #pragma unroll
                for (int c = 0; c < 8; ++c) {
                    float cp = of[5*c];
                    float cg = tf[5*c];
                    float coord = 0.0f;
                    #pragma unroll
                    for (int k = 1; k < 5; ++k) {
                        float d = of[5*c + k] - tf[5*c + k];
                        coord = fmaf(d, d, coord);
                    }
                    float dm1 = cp - 1.0f;
                    float obj = fmaf(LAMBDA_COOR, coord, dm1 * dm1);
                    float nob = LAMBDA_NOOBJ * cp * cp;
                    acc += (cg > 0.0f) ? obj : nob;
                }
            }
        } else {
            // Generic tail: one group (4 cells) at a time.
            for (int g = g0; g < n_groups; ++g) {
                const float4* o4 = (const float4*)(outp + (size_t)g * 20);
                const float4* t4 = (const float4*)(tgt  + (size_t)g * 20);
                float o[20], t[20];
                #pragma unroll
                for (int i = 0; i < 5; ++i) {
                    float4 a = o4[i];
                    float4 b = t4[i];
                    o[4*i+0] = a.x; o[4*i+1] = a.y; o[4*i+2] = a.z; o[4*i+3] = a.w;
                    t[4*i+0] = b.x; t[4*i+1] = b.y; t[4*i+2] = b.z; t[4*i+3] = b.w;
                }
                #pragma unroll
                for (int c = 0; c < 4; ++c) {
                    float cp = o[5*c];
                    float cg = t[5*c];
                    float coord = 0.0f;
                    #pragma unroll
                    for (int k = 1; k < 5; ++k) {
                        float d = o[5*c + k] - t[5*c + k];
                        coord = fmaf(d, d, coord);
                    }
                    float dm1 = cp - 1.0f;
                    float obj = fmaf(LAMBDA_COOR, coord, dm1 * dm1);
                    float nob = LAMBDA_NOOBJ * cp * cp;
                    acc += (cg > 0.0f) ? obj : nob;
                }
            }
        }
    }

    // 64-lane wave reduction
    #pragma unroll
    for (int off = 32; off > 0; off >>= 1)
        acc += __shfl_down(acc, off, 64);

    __shared__ float wave_sums[4];  // 256 threads / 64 lanes
    int lane = threadIdx.x & 63;
    int wid  = threadIdx.x >> 6;
    if (lane == 0) wave_sums[wid] = acc;
    __syncthreads();

    if (threadIdx.x == 0) {
        float s = wave_sums[0] + wave_sums[1] + wave_sums[2] + wave_sums[3];
        atomicAdd(loss, s * inv_b);
    }
}

extern "C" void kernel_launch(void* const* d_in, const int* in_sizes, int n_in,
                              void* d_out, int out_size, void* d_ws, size_t ws_size,
                              hipStream_t stream) {
    const float* outputs = (const float*)d_in[0];
    const float* targets = (const float*)d_in[1];
    float* loss = (float*)d_out;

    const int n_elems  = in_sizes[0];          // 128*256*256*5 = 41,943,040
    const int n_groups = n_elems / 20;         // 2,097,152 groups of 4 cells
    const float inv_b  = 1.0f / 128.0f;        // B = 128

    // d_out is poisoned before every timed launch; zero it on-stream.
    hipMemsetAsync(d_out, 0, sizeof(float), stream);

    const int threads = 256;
    const int blocks  = 2048;                  // 2048*256*4 == n_groups exactly
    yolo_loss_kernel<<<blocks, threads, 0, stream>>>(
        outputs, targets, loss, n_groups, inv_b);
}

// Round 3
// 332.392 us; speedup vs baseline: 1.1868x; 1.1868x over previous
//
#include <hip/hip_runtime.h>
#include <stdint.h>

#define LAMBDA_COOR 5.0f
#define LAMBDA_NOOBJ 0.5f

// Per-wave async streaming pipeline via global_load_lds:
//  - each wave owns a private double-buffered LDS region (2 slots x (5KB o + 5KB t))
//  - a tile = 64 groups = 1280 floats per array, staged with 10x
//    global_load_lds_dwordx4 (1KB in flight per instruction, ZERO VGPRs held)
//  - counted s_waitcnt vmcnt(10): while tile j is consumed, tile j+1's 10 loads
//    stay in flight; tile j+2 is issued right after (never drain mid-loop)
//  - no __syncthreads anywhere: wave w consumes exactly what wave w staged
// In-flight per CU: 8 waves x 20KB = 160KB -> latency-insensitive, vs ~2KB/wave
// in the VGPR-staged versions (compiler capped VGPR_Count at 32 and serialized).

typedef __attribute__((address_space(3))) uint8_t as3_t;
typedef __attribute__((address_space(1))) uint8_t as1_t;

__device__ __forceinline__ void gload16(const void* gptr, void* lptr) {
    // 16B per lane, direct global->LDS, LDS dest = wave-uniform base + lane*16
    __builtin_amdgcn_global_load_lds((const as1_t*)gptr, (as3_t*)lptr, 16, 0, 0);
}

__global__ __launch_bounds__(256) void yolo_loss_kernel(
    const float* __restrict__ outp, const float* __restrict__ tgt,
    float* __restrict__ loss, int n_groups, float inv_b)
{
    __shared__ float lds[4][2][2][1280];   // [wave][slot][o/t][floats] = 80 KiB

    const int lane = threadIdx.x & 63;
    const int wid  = threadIdx.x >> 6;
    const int W    = blockIdx.x * 4 + wid;         // global wave id
    const int NW   = gridDim.x * 4;                // total waves

    const int F = n_groups >> 6;                   // number of full 64-group tiles
    // wave W owns tiles t = W + j*NW, j = 0..m-1
    const int m = (W < F) ? ((F - 1 - W) / NW + 1) : 0;

    const float4* o4 = (const float4*)outp;
    const float4* t4 = (const float4*)tgt;

    float acc = 0.0f;

    auto issue = [&](int j, int slot) {
        const long cb = ((long)W + (long)j * NW) * 320;  // float4-chunk base of tile
        float* lo = &lds[wid][slot][0][0];
        float* lt = &lds[wid][slot][1][0];
        #pragma unroll
        for (int k = 0; k < 5; ++k)
            gload16(o4 + cb + k * 64 + lane, lo + k * 256);
        #pragma unroll
        for (int k = 0; k < 5; ++k)
            gload16(t4 + cb + k * 64 + lane, lt + k * 256);
    };

    if (m > 0) issue(0, 0);
    if (m > 1) issue(1, 1);

    #pragma unroll 1
    for (int j = 0; j < m; ++j) {
        const int s = j & 1;
        // tile j is the oldest 10 outstanding loads; keep tile j+1 in flight
        if (j + 1 < m) { asm volatile("s_waitcnt vmcnt(10)" ::: "memory"); }
        else           { asm volatile("s_waitcnt vmcnt(0)"  ::: "memory"); }
        __builtin_amdgcn_sched_barrier(0);   // don't hoist ds_read above the wait

        const float4* po = (const float4*)&lds[wid][s][0][lane * 20];
        const float4* pt = (const float4*)&lds[wid][s][1][lane * 20];
        float o[20], t[20];
        #pragma unroll
        for (int i = 0; i < 5; ++i) {
            float4 a = po[i], b = pt[i];
            o[4*i+0] = a.x; o[4*i+1] = a.y; o[4*i+2] = a.z; o[4*i+3] = a.w;
            t[4*i+0] = b.x; t[4*i+1] = b.y; t[4*i+2] = b.z; t[4*i+3] = b.w;
        }
        #pragma unroll
        for (int c = 0; c < 4; ++c) {
            float cp = o[5*c];
            float cg = t[5*c];
            float coord = 0.0f;
            #pragma unroll
            for (int k = 1; k < 5; ++k) {
                float d = o[5*c + k] - t[5*c + k];
                coord = fmaf(d, d, coord);
            }
            float dm1 = cp - 1.0f;
            float obj = fmaf(LAMBDA_COOR, coord, dm1 * dm1);
            float nob = LAMBDA_NOOBJ * cp * cp;
            acc += (cg > 0.0f) ? obj : nob;
        }

        if (j + 2 < m) {
            // slot s reads are done before its overwrite begins
            asm volatile("s_waitcnt lgkmcnt(0)" ::: "memory");
            __builtin_amdgcn_sched_barrier(0);
            issue(j + 2, s);
        }
    }

    // Leftover groups (n_groups % 64) — empty for the bench shape.
    {
        const int gstart = F << 6;
        const int gtid   = blockIdx.x * blockDim.x + threadIdx.x;
        const int nth    = gridDim.x * blockDim.x;
        for (int g = gstart + gtid; g < n_groups; g += nth) {
            const float4* og = (const float4*)(outp + (size_t)g * 20);
            const float4* tg = (const float4*)(tgt  + (size_t)g * 20);
            float o[20], t[20];
            #pragma unroll
            for (int i = 0; i < 5; ++i) {
                float4 a = og[i], b = tg[i];
                o[4*i+0] = a.x; o[4*i+1] = a.y; o[4*i+2] = a.z; o[4*i+3] = a.w;
                t[4*i+0] = b.x; t[4*i+1] = b.y; t[4*i+2] = b.z; t[4*i+3] = b.w;
            }
            #pragma unroll
            for (int c = 0; c < 4; ++c) {
                float cp = o[5*c], cg = t[5*c];
                float coord = 0.0f;
                #pragma unroll
                for (int k = 1; k < 5; ++k) {
                    float d = o[5*c + k] - t[5*c + k];
                    coord = fmaf(d, d, coord);
                }
                float dm1 = cp - 1.0f;
                float obj = fmaf(LAMBDA_COOR, coord, dm1 * dm1);
                float nob = LAMBDA_NOOBJ * cp * cp;
                acc += (cg > 0.0f) ? obj : nob;
            }
        }
    }

    // 64-lane wave reduction
    #pragma unroll
    for (int off = 32; off > 0; off >>= 1)
        acc += __shfl_down(acc, off, 64);

    __shared__ float wave_sums[4];
    if (lane == 0) wave_sums[wid] = acc;
    __syncthreads();

    if (threadIdx.x == 0) {
        float s = wave_sums[0] + wave_sums[1] + wave_sums[2] + wave_sums[3];
        atomicAdd(loss, s * inv_b);
    }
}

extern "C" void kernel_launch(void* const* d_in, const int* in_sizes, int n_in,
                              void* d_out, int out_size, void* d_ws, size_t ws_size,
                              hipStream_t stream) {
    const float* outputs = (const float*)d_in[0];
    const float* targets = (const float*)d_in[1];
    float* loss = (float*)d_out;

    const int n_elems  = in_sizes[0];          // 128*256*256*5 = 41,943,040
    const int n_groups = n_elems / 20;         // 2,097,152 groups of 4 cells
    const float inv_b  = 1.0f / 128.0f;        // B = 128

    // d_out is poisoned before every timed launch; zero it on-stream.
    hipMemsetAsync(d_out, 0, sizeof(float), stream);

    const int threads = 256;
    const int blocks  = 512;   // 80KB LDS/block -> 2 blocks/CU, 2048 waves,
                               // 16 tiles/wave: 512*4*64*16 == n_groups exactly
    yolo_loss_kernel<<<blocks, threads, 0, stream>>>(
        outputs, targets, loss, n_groups, inv_b);
}